// Round 1
// 1169.355 us; speedup vs baseline: 1.0690x; 1.0690x over previous
//
#include <hip/hip_runtime.h>
#include <hip/hip_bf16.h>

typedef short v8s __attribute__((ext_vector_type(8)));
typedef float v4f __attribute__((ext_vector_type(4)));

// ---------------------------------------------------------------------------
// JAX threefry2x32 replication (partitionable mode verified in round 1).
// keep  <=>  (o0^o1) < 2^31   for p = 0.5.
// ---------------------------------------------------------------------------
__host__ __device__ __forceinline__ unsigned rotl32(unsigned x, int d) {
  return (x << d) | (x >> (32 - d));
}

__host__ __device__ __forceinline__ void threefry2x32(
    unsigned k0, unsigned k1, unsigned x0, unsigned x1,
    unsigned& o0, unsigned& o1) {
  unsigned ks2 = k0 ^ k1 ^ 0x1BD11BDAu;
  unsigned v0 = x0 + k0, v1 = x1 + k1;
#define TF_R(r) { v0 += v1; v1 = rotl32(v1, (r)); v1 ^= v0; }
  TF_R(13) TF_R(15) TF_R(26) TF_R(6)  v0 += k1;  v1 += ks2 + 1u;
  TF_R(17) TF_R(29) TF_R(16) TF_R(24) v0 += ks2; v1 += k0 + 2u;
  TF_R(13) TF_R(15) TF_R(26) TF_R(6)  v0 += k0;  v1 += k1 + 3u;
  TF_R(17) TF_R(29) TF_R(16) TF_R(24) v0 += k1;  v1 += ks2 + 4u;
  TF_R(13) TF_R(15) TF_R(26) TF_R(6)  v0 += ks2; v1 += k0 + 5u;
#undef TF_R
  o0 = v0; o1 = v1;
}

__device__ __forceinline__ float drop_scale(unsigned ka, unsigned kb,
                                            unsigned pos) {
  unsigned o0, o1;
  threefry2x32(ka, kb, 0u, pos, o0, o1);
  return ((o0 ^ o1) >> 31) ? 0.0f : 2.0f;
}

__device__ __forceinline__ float bf2f(unsigned short u) {
  unsigned x = ((unsigned)u) << 16;
  float f;
  __builtin_memcpy(&f, &x, 4);
  return f;
}
__device__ __forceinline__ unsigned short f2bf(float f) {
  __hip_bfloat16 h = __float2bfloat16(f);
  unsigned short u;
  __builtin_memcpy(&u, &h, 2);
  return u;
}

// ---------------------------------------------------------------------------
// Zero both degree arrays in one launch (replaces 4 hipMemsetAsync).
// ---------------------------------------------------------------------------
__global__ __launch_bounds__(256) void k_zero(int* __restrict__ a, int na,
                                              int* __restrict__ b, int nb) {
  int i = blockIdx.x * 256 + threadIdx.x;
  if (i < na) a[i] = 0;
  if (i < nb) b[i] = 0;
}

// ---------------------------------------------------------------------------
// Weight prep: W1T[n*128+k] = bf16(W1[k*256+n]);
// W2 split-precision transpose: W2T_{hi,lo}[n*256+k], n padded to 48.
// ---------------------------------------------------------------------------
__global__ __launch_bounds__(256) void k_prep(
    const float* __restrict__ W1, unsigned short* __restrict__ W1T,
    const float* __restrict__ W2, unsigned short* __restrict__ W2Th,
    unsigned short* __restrict__ W2Tl) {
  int tid = blockIdx.x * 256 + threadIdx.x;
  if (tid < 32768) {
    int n = tid >> 7, k = tid & 127;
    W1T[n * 128 + k] = f2bf(W1[k * 256 + n]);
  } else if (tid < 32768 + 48 * 256) {
    int i = tid - 32768;
    int n = i >> 8, k = i & 255;
    float w = (n < 47) ? W2[k * 47 + n] : 0.f;
    unsigned short hi = f2bf(w);
    float r = w - bf2f(hi);
    W2Th[n * 256 + k] = hi;
    W2Tl[n * 256 + k] = f2bf(r);
  }
}

// ---------------------------------------------------------------------------
// CSR build (both graphs in single launches): count, scan x3, fill
// ---------------------------------------------------------------------------
__global__ __launch_bounds__(256) void k_countm(
    const int* __restrict__ dst1, int* __restrict__ deg1, int E1,
    const int* __restrict__ dst0, int* __restrict__ deg0, int E0) {
  int e = blockIdx.x * 256 + threadIdx.x;
  if (e < E1) {
    atomicAdd(&deg1[dst1[e]], 1);
  } else {
    int e0 = e - E1;
    if (e0 < E0) atomicAdd(&deg0[dst0[e0]], 1);
  }
}

// pass 1: per-1024 chunk exclusive scan; two independent segments by block.
__global__ __launch_bounds__(256) void k_scan1m(
    const int* __restrict__ d1, int* __restrict__ o1, int* __restrict__ b1,
    int n1, int B1,
    const int* __restrict__ d0, int* __restrict__ o0, int* __restrict__ b0,
    int n0) {
  __shared__ int ls[256];
  const int* d; int* o; int* bs; int n; int blk;
  if ((int)blockIdx.x < B1) {
    d = d1; o = o1; bs = b1; n = n1; blk = blockIdx.x;
  } else {
    d = d0; o = o0; bs = b0; n = n0; blk = blockIdx.x - B1;
  }
  int t = threadIdx.x;
  int base = blk * 1024 + t * 4;
  int v[4], s = 0;
#pragma unroll
  for (int q = 0; q < 4; ++q) {
    int i = base + q;
    v[q] = (i < n) ? d[i] : 0;
    s += v[q];
  }
  ls[t] = s;
  __syncthreads();
  for (int off = 1; off < 256; off <<= 1) {
    int x = (t >= off) ? ls[t - off] : 0;
    __syncthreads();
    ls[t] += x;
    __syncthreads();
  }
  int run = ls[t] - s;
  if (t == 255) bs[blk] = ls[255];
#pragma unroll
  for (int q = 0; q < 4; ++q) {
    int i = base + q;
    if (i < n) o[i] = run;
    run += v[q];
  }
}

// single-chunk exclusive scan helper (n <= 1024), one block.
__device__ __forceinline__ void scan_chunk(const int* __restrict__ d,
                                           int* __restrict__ o, int n,
                                           int* ls) {
  int t = threadIdx.x;
  int base = t * 4;
  int v[4], s = 0;
#pragma unroll
  for (int q = 0; q < 4; ++q) {
    int i = base + q;
    v[q] = (i < n) ? d[i] : 0;
    s += v[q];
  }
  ls[t] = s;
  __syncthreads();
  for (int off = 1; off < 256; off <<= 1) {
    int x = (t >= off) ? ls[t - off] : 0;
    __syncthreads();
    ls[t] += x;
    __syncthreads();
  }
  int run = ls[t] - s;
#pragma unroll
  for (int q = 0; q < 4; ++q) {
    int i = base + q;
    if (i < n) o[i] = run;
    run += v[q];
  }
}

// pass 2: scan both block-sum arrays in one single-block launch.
__global__ __launch_bounds__(256) void k_scanmid(
    const int* __restrict__ b1, int* __restrict__ x1, int B1,
    const int* __restrict__ b0, int* __restrict__ x0, int B0) {
  __shared__ int ls[256];
  scan_chunk(b1, x1, B1, ls);
  __syncthreads();
  scan_chunk(b0, x0, B0, ls);
}

// pass 3: add scanned block sums; also emit mutable cursor copy woff[0..N).
__global__ __launch_bounds__(256) void k_scan3m(
    int* __restrict__ o1, int* __restrict__ w1, const int* __restrict__ x1,
    int n1, int B1,
    int* __restrict__ o0, int* __restrict__ w0, const int* __restrict__ x0,
    int n0) {
  int* o; int* w; const int* xx; int n; int blk;
  if ((int)blockIdx.x < B1) {
    o = o1; w = w1; xx = x1; n = n1; blk = blockIdx.x;
  } else {
    o = o0; w = w0; xx = x0; n = n0; blk = blockIdx.x - B1;
  }
  int t = threadIdx.x;
  int add = xx[blk];
  int base = blk * 1024 + t * 4;
#pragma unroll
  for (int q = 0; q < 4; ++q) {
    int i = base + q;
    if (i < n) {
      int v = o[i] + add;
      o[i] = v;
      if (i < n - 1) w[i] = v;   // cursor copy for fill (N entries)
    }
  }
}

// fill: csr[pos] = {r, sel[r]} ; cursor = atomic on woff (scanned copy)
__global__ __launch_bounds__(256) void k_fillm(
    const int* __restrict__ src1, const int* __restrict__ dst1,
    const int* __restrict__ s2, int* __restrict__ woff1,
    int2* __restrict__ csr1, int E1,
    const int* __restrict__ src0, const int* __restrict__ dst0,
    const int* __restrict__ s1, int* __restrict__ woff0,
    int2* __restrict__ csr0, int E0) {
  int e = blockIdx.x * 256 + threadIdx.x;
  if (e < E1) {
    int d = dst1[e];
    int pos = atomicAdd(&woff1[d], 1);
    int r = src1[e];
    csr1[pos] = make_int2(r, s2[r]);
  } else {
    int e0 = e - E1;
    if (e0 < E0) {
      int d = dst0[e0];
      int pos = atomicAdd(&woff0[d], 1);
      int r = src0[e0];
      csr0[pos] = make_int2(r, s1[r]);
    }
  }
}

// ---------------------------------------------------------------------------
// Merged aggregation d=128 (hop1 nodes 0..N1-1, hop0 nodes N1..Ntot-1).
// One wave per dst node. lane owns cols {2l, 2l+1}. x2 unroll for load ILP
// (accumulation order preserved -> bit-identical results).
// ---------------------------------------------------------------------------
__global__ __launch_bounds__(256) void k_agg128m(
    const float* __restrict__ feats,
    const int* __restrict__ off1, const int2* __restrict__ csr1,
    const int* __restrict__ sel1,
    const int* __restrict__ off0, const int2* __restrict__ csr0,
    const int* __restrict__ sel0,
    unsigned short* __restrict__ outbf, int N1, int Ntot,
    unsigned k1fa, unsigned k1fb, unsigned k1ha, unsigned k1hb,
    unsigned k0fa, unsigned k0fb, unsigned k0ha, unsigned k0hb) {
  int wave = (blockIdx.x * 256 + threadIdx.x) >> 6;
  int lane = threadIdx.x & 63;
  if (wave >= Ntot) return;
  const int* off; const int2* csr; const int* sel;
  unsigned kfa, kfb, kha, khb; int w;
  if (wave < N1) {
    off = off1; csr = csr1; sel = sel1;
    kfa = k1fa; kfb = k1fb; kha = k1ha; khb = k1hb; w = wave;
  } else {
    off = off0; csr = csr0; sel = sel0;
    kfa = k0fa; kfb = k0fb; kha = k0ha; khb = k0hb; w = wave - N1;
  }
  int beg = off[w], end = off[w + 1];
  float acc0 = 0.f, acc1 = 0.f;
  for (int base = beg; base < end; base += 64) {
    int idx = base + lane;
    int2 rg = make_int2(0, 0);
    if (idx < end) rg = csr[idx];
    int r_l = rg.x, g_l = rg.y;
    int cnt = min(64, end - base);
    int b = 0;
    for (; b + 2 <= cnt; b += 2) {
      int ra = __shfl(r_l, b),     ga = __shfl(g_l, b);
      int rb = __shfl(r_l, b + 1), gb = __shfl(g_l, b + 1);
      float2 fa = *(const float2*)(feats + (size_t)ga * 128 + lane * 2);
      float2 fb = *(const float2*)(feats + (size_t)gb * 128 + lane * 2);
      unsigned pa = (unsigned)ra * 128u + (unsigned)(lane * 2);
      unsigned pb = (unsigned)rb * 128u + (unsigned)(lane * 2);
      acc0 += fa.x * drop_scale(kfa, kfb, pa);
      acc1 += fa.y * drop_scale(kfa, kfb, pa + 1);
      acc0 += fb.x * drop_scale(kfa, kfb, pb);
      acc1 += fb.y * drop_scale(kfa, kfb, pb + 1);
    }
    if (b < cnt) {
      int r = __shfl(r_l, b), g = __shfl(g_l, b);
      float2 f = *(const float2*)(feats + (size_t)g * 128 + lane * 2);
      unsigned p = (unsigned)r * 128u + (unsigned)(lane * 2);
      acc0 += f.x * drop_scale(kfa, kfb, p);
      acc1 += f.y * drop_scale(kfa, kfb, p + 1);
    }
  }
  float deg = (float)(end - beg);
  float inv = deg > 0.f ? 1.0f / deg : 0.f;
  float n0 = acc0 * inv, n1 = acc1 * inv;
  float2 sf = *(const float2*)(feats + (size_t)sel[w] * 128 + lane * 2);
  unsigned ps = (unsigned)w * 128u + (unsigned)(lane * 2);
  float v0 = n0 + sf.x * drop_scale(kha, khb, ps);
  float v1 = n1 + sf.y * drop_scale(kha, khb, ps + 1);
  v0 = v0 > 0.f ? v0 : 0.f;
  v1 = v1 > 0.f ? v1 : 0.f;
  ushort2 u;
  u.x = f2bf(v0);
  u.y = f2bf(v1);
  *(ushort2*)(outbf + (size_t)wave * 128 + lane * 2) = u;
}

// ---------------------------------------------------------------------------
// Aggregation d=256 over bf16 rows: one wave per dst. lane owns cols 4l..4l+3.
// ---------------------------------------------------------------------------
__global__ __launch_bounds__(256) void k_agg256(
    const unsigned short* __restrict__ X, const int* __restrict__ off,
    const int2* __restrict__ csr, const unsigned short* __restrict__ self,
    unsigned short* __restrict__ outbf, int N,
    unsigned kfa, unsigned kfb, unsigned kha, unsigned khb) {
  int wave = (blockIdx.x * 256 + threadIdx.x) >> 6;
  int lane = threadIdx.x & 63;
  if (wave >= N) return;
  int beg = off[wave], end = off[wave + 1];
  float acc[4] = {0.f, 0.f, 0.f, 0.f};
  for (int base = beg; base < end; base += 64) {
    int idx = base + lane;
    int r_l = 0;
    if (idx < end) r_l = csr[idx].x;
    int cnt = min(64, end - base);
    for (int b = 0; b < cnt; ++b) {
      int r = __shfl(r_l, b);
      ushort4 raw = ((const ushort4*)(X + (size_t)r * 256))[lane];
      unsigned p = (unsigned)r * 256u + (unsigned)(lane * 4);
      acc[0] += bf2f(raw.x) * drop_scale(kfa, kfb, p);
      acc[1] += bf2f(raw.y) * drop_scale(kfa, kfb, p + 1);
      acc[2] += bf2f(raw.z) * drop_scale(kfa, kfb, p + 2);
      acc[3] += bf2f(raw.w) * drop_scale(kfa, kfb, p + 3);
    }
  }
  float deg = (float)(end - beg);
  float inv = deg > 0.f ? 1.0f / deg : 0.f;
  ushort4 sr = ((const ushort4*)(self + (size_t)wave * 256))[lane];
  unsigned ps = (unsigned)wave * 256u + (unsigned)(lane * 4);
  float sv[4] = {bf2f(sr.x), bf2f(sr.y), bf2f(sr.z), bf2f(sr.w)};
  ushort4 u;
  unsigned short* up = (unsigned short*)&u;
#pragma unroll
  for (int c = 0; c < 4; ++c) {
    float v = acc[c] * inv + sv[c] * drop_scale(kha, khb, ps + c);
    up[c] = f2bf(v > 0.f ? v : 0.f);
  }
  ((ushort4*)(outbf + (size_t)wave * 256))[lane] = u;
}

// ---------------------------------------------------------------------------
// GEMM1: C[M,256](bf16) = A[M,128](bf16) @ W1 + b1, via MFMA 16x16x32 bf16.
// grid (ceil(M/128), 2). Block 256 = 4 waves, each wave a 64x64 C sub-tile.
// ---------------------------------------------------------------------------
__global__ __launch_bounds__(256) void k_gemm1(
    const unsigned short* __restrict__ A, const unsigned short* __restrict__ W1T,
    const float* __restrict__ bias, unsigned short* __restrict__ C, int M) {
  __shared__ unsigned short As[128 * 72];
  __shared__ unsigned short Bs[128 * 72];
  const int t = threadIdx.x;
  const int r0 = blockIdx.x * 128, n0 = blockIdx.y * 128;
  const int wv = t >> 6, lane = t & 63;
  const int mb = (wv >> 1) * 64, nb = (wv & 1) * 64;
  const int qm = lane & 15, quad = lane >> 4;
  v4f acc[4][4];
#pragma unroll
  for (int i = 0; i < 4; ++i)
#pragma unroll
    for (int j = 0; j < 4; ++j) acc[i][j] = (v4f){0.f, 0.f, 0.f, 0.f};

  for (int kt = 0; kt < 128; kt += 64) {
#pragma unroll
    for (int it = 0; it < 4; ++it) {
      int i = t + it * 256;            // 0..1023
      int r = i >> 3, c = i & 7;
      uint4 v = make_uint4(0, 0, 0, 0);
      int gr = r0 + r;
      if (gr < M) v = ((const uint4*)A)[(size_t)gr * 16 + (kt >> 3) + c];
      *(uint4*)&As[r * 72 + c * 8] = v;
    }
#pragma unroll
    for (int it = 0; it < 4; ++it) {
      int i = t + it * 256;
      int n = i >> 3, c = i & 7;
      uint4 v = ((const uint4*)W1T)[(size_t)(n0 + n) * 16 + (kt >> 3) + c];
      *(uint4*)&Bs[n * 72 + c * 8] = v;
    }
    __syncthreads();
#pragma unroll
    for (int kk = 0; kk < 64; kk += 32) {
      v8s af[4], bf_[4];
#pragma unroll
      for (int i = 0; i < 4; ++i)
        af[i] = *(const v8s*)&As[(mb + i * 16 + qm) * 72 + kk + quad * 8];
#pragma unroll
      for (int j = 0; j < 4; ++j)
        bf_[j] = *(const v8s*)&Bs[(nb + j * 16 + qm) * 72 + kk + quad * 8];
#pragma unroll
      for (int i = 0; i < 4; ++i)
#pragma unroll
        for (int j = 0; j < 4; ++j)
          acc[i][j] = __builtin_amdgcn_mfma_f32_16x16x32_bf16(
              af[i], bf_[j], acc[i][j], 0, 0, 0);
    }
    __syncthreads();
  }
  // epilogue: D col = lane&15, row = quad*4 + reg (m89-verified)
  const int col_base = n0 + nb + qm;
  float bj[4];
#pragma unroll
  for (int j = 0; j < 4; ++j) bj[j] = bias[col_base + j * 16];
#pragma unroll
  for (int i = 0; i < 4; ++i) {
    int row = r0 + mb + i * 16 + quad * 4;
#pragma unroll
    for (int reg = 0; reg < 4; ++reg) {
      int rr = row + reg;
      if (rr < M) {
#pragma unroll
        for (int j = 0; j < 4; ++j)
          C[(size_t)rr * 256 + col_base + j * 16] = f2bf(acc[i][j][reg] + bj[j]);
      }
    }
  }
}

// ---------------------------------------------------------------------------
// GEMM2 (MFMA): out[M,47](f32) = A[M,256](bf16) @ (W2hi+W2lo) + b2.
// Block = 64 rows (4 waves x 16 rows); N padded to 48 (3 col-tiles).
// Split-precision W2 keeps f32-level weight accuracy.
// ---------------------------------------------------------------------------
__global__ __launch_bounds__(256) void k_gemm2(
    const unsigned short* __restrict__ A, const unsigned short* __restrict__ Bh,
    const unsigned short* __restrict__ Bl, const float* __restrict__ b2,
    float* __restrict__ out, int M) {
  const int t = threadIdx.x;
  const int wv = t >> 6, lane = t & 63;
  const int qm = lane & 15, quad = lane >> 4;
  const int rw = blockIdx.x * 64 + wv * 16;
  v4f acc[3];
#pragma unroll
  for (int j = 0; j < 3; ++j) acc[j] = (v4f){0.f, 0.f, 0.f, 0.f};
  int arow = rw + qm;
  if (arow >= M) arow = M - 1;                 // clamp; masked at store
  const unsigned short* Ar = A + (size_t)arow * 256;
#pragma unroll
  for (int kk = 0; kk < 256; kk += 32) {
    v8s af = *(const v8s*)&Ar[kk + quad * 8];
#pragma unroll
    for (int j = 0; j < 3; ++j) {
      v8s bh = *(const v8s*)&Bh[(size_t)(j * 16 + qm) * 256 + kk + quad * 8];
      v8s bl = *(const v8s*)&Bl[(size_t)(j * 16 + qm) * 256 + kk + quad * 8];
      acc[j] = __builtin_amdgcn_mfma_f32_16x16x32_bf16(af, bh, acc[j], 0, 0, 0);
      acc[j] = __builtin_amdgcn_mfma_f32_16x16x32_bf16(af, bl, acc[j], 0, 0, 0);
    }
  }
#pragma unroll
  for (int j = 0; j < 3; ++j) {
    int col = j * 16 + qm;
    if (col >= 47) continue;
    float bb = b2[col];
#pragma unroll
    for (int reg = 0; reg < 4; ++reg) {
      int row = rw + quad * 4 + reg;
      if (row < M) out[(size_t)row * 47 + col] = acc[j][reg] + bb;
    }
  }
}

// ---------------------------------------------------------------------------
// Launch
// ---------------------------------------------------------------------------
static inline size_t alignup(size_t x) { return (x + 255) & ~(size_t)255; }

extern "C" void kernel_launch(void* const* d_in, const int* in_sizes, int n_in,
                              void* d_out, int out_size, void* d_ws,
                              size_t ws_size, hipStream_t stream) {
  const float* features = (const float*)d_in[0];
  const int* s0   = (const int*)d_in[1];
  const int* s1   = (const int*)d_in[2];
  const int* s2   = (const int*)d_in[3];
  const int* src0 = (const int*)d_in[4];
  const int* dst0 = (const int*)d_in[5];
  const int* src1 = (const int*)d_in[6];
  const int* dst1 = (const int*)d_in[7];
  const float* W1 = (const float*)d_in[8];
  const float* b1 = (const float*)d_in[9];
  const float* W2 = (const float*)d_in[10];
  const float* b2 = (const float*)d_in[11];
  float* out = (float*)d_out;

  const int N0 = in_sizes[1], N1 = in_sizes[2];
  const int E0 = in_sizes[4], E1 = in_sizes[6];
  const int Ntot = N1 + N0;
  const int Etot = E1 + E0;

  // ---- key derivation (partitionable; verified round 1) ----
  unsigned dk[3][2], kfs[3][2], khs[3][2];
  for (int i = 0; i < 3; ++i)
    threefry2x32(0u, 42u, 0u, (unsigned)i, dk[i][0], dk[i][1]);
  for (int i = 0; i < 3; ++i) {
    threefry2x32(dk[i][0], dk[i][1], 0u, 0u, kfs[i][0], kfs[i][1]);
    threefry2x32(dk[i][0], dk[i][1], 0u, 1u, khs[i][0], khs[i][1]);
  }

  // ---- workspace layout ----
  char* p = (char*)d_ws;
  auto take = [&](size_t bytes) {
    char* r = p;
    p += alignup(bytes);
    return r;
  };
  // a_all rows: [0,N1) = hop1 agg out; [N1,Ntot) = hop0 agg out.
  unsigned short* a_all = (unsigned short*)take((size_t)Ntot * 128 * 2);
  unsigned short* n_all = (unsigned short*)take((size_t)Ntot * 256 * 2);
  unsigned short* a2bf  = (unsigned short*)take((size_t)N0 * 256 * 2);
  unsigned short* w1t   = (unsigned short*)take(256 * 128 * 2);
  unsigned short* w2th  = (unsigned short*)take(48 * 256 * 2);
  unsigned short* w2tl  = (unsigned short*)take(48 * 256 * 2);
  int* off1  = (int*)take((size_t)(N1 + 2) * 4);
  int* woff1 = (int*)take((size_t)N1 * 4);
  int* deg1  = (int*)take((size_t)(N1 + 2) * 4);
  int* off0  = (int*)take((size_t)(N0 + 2) * 4);
  int* woff0 = (int*)take((size_t)N0 * 4);
  int* deg0  = (int*)take((size_t)(N0 + 2) * 4);
  int* bs1   = (int*)take(1024 * 4);
  int* bs0   = (int*)take(1024 * 4);
  int* bx1   = (int*)take(1024 * 4);
  int* bx0   = (int*)take(1024 * 4);
  int2* csr1 = (int2*)take((size_t)E1 * 8);
  int2* csr0 = (int2*)take((size_t)E0 * 8);

  k_zero<<<(N1 + 2 + 255) / 256, 256, 0, stream>>>(deg1, N1 + 2, deg0, N0 + 2);
  k_prep<<<(32768 + 48 * 256 + 255) / 256, 256, 0, stream>>>(W1, w1t, W2, w2th,
                                                             w2tl);
  k_countm<<<(Etot + 255) / 256, 256, 0, stream>>>(dst1, deg1, E1, dst0, deg0,
                                                   E0);

  const int n1s = N1 + 1, B1 = (n1s + 1023) / 1024;
  const int n0s = N0 + 1, B0 = (n0s + 1023) / 1024;
  k_scan1m<<<B1 + B0, 256, 0, stream>>>(deg1, off1, bs1, n1s, B1,
                                        deg0, off0, bs0, n0s);
  k_scanmid<<<1, 256, 0, stream>>>(bs1, bx1, B1, bs0, bx0, B0);
  k_scan3m<<<B1 + B0, 256, 0, stream>>>(off1, woff1, bx1, n1s, B1,
                                        off0, woff0, bx0, n0s);

  k_fillm<<<(Etot + 255) / 256, 256, 0, stream>>>(
      src1, dst1, s2, woff1, csr1, E1,
      src0, dst0, s1, woff0, csr0, E0);

  // layer 0, both hops in one launch: rows [0,N1) hop1, [N1,Ntot) hop0
  k_agg128m<<<(Ntot + 3) / 4, 256, 0, stream>>>(
      features, off1, csr1, s1, off0, csr0, s0, a_all, N1, Ntot,
      kfs[1][0], kfs[1][1], khs[1][0], khs[1][1],
      kfs[0][0], kfs[0][1], khs[0][0], khs[0][1]);
  {
    dim3 g((Ntot + 127) / 128, 2);
    k_gemm1<<<g, 256, 0, stream>>>(a_all, w1t, b1, n_all, Ntot);
  }

  // layer 1: a = agg(graph0, n1, n0) ; out = a@W2+b2
  k_agg256<<<(N0 + 3) / 4, 256, 0, stream>>>(
      n_all, off0, csr0, n_all + (size_t)N1 * 256, a2bf, N0,
      kfs[2][0], kfs[2][1], khs[2][0], khs[2][1]);
  k_gemm2<<<(N0 + 63) / 64, 256, 0, stream>>>(a2bf, w2th, w2tl, b2, out, N0);
}

// Round 2
// 1156.742 us; speedup vs baseline: 1.0806x; 1.0109x over previous
//
#include <hip/hip_runtime.h>
#include <hip/hip_bf16.h>

typedef short v8s __attribute__((ext_vector_type(8)));
typedef float v4f __attribute__((ext_vector_type(4)));

// ---------------------------------------------------------------------------
// JAX threefry2x32 replication (partitionable mode verified in round 1).
// keep  <=>  (o0^o1) < 2^31   for p = 0.5.
// ---------------------------------------------------------------------------
__host__ __device__ __forceinline__ unsigned rotl32(unsigned x, int d) {
  return (x << d) | (x >> (32 - d));
}

__host__ __device__ __forceinline__ void threefry2x32(
    unsigned k0, unsigned k1, unsigned x0, unsigned x1,
    unsigned& o0, unsigned& o1) {
  unsigned ks2 = k0 ^ k1 ^ 0x1BD11BDAu;
  unsigned v0 = x0 + k0, v1 = x1 + k1;
#define TF_R(r) { v0 += v1; v1 = rotl32(v1, (r)); v1 ^= v0; }
  TF_R(13) TF_R(15) TF_R(26) TF_R(6)  v0 += k1;  v1 += ks2 + 1u;
  TF_R(17) TF_R(29) TF_R(16) TF_R(24) v0 += ks2; v1 += k0 + 2u;
  TF_R(13) TF_R(15) TF_R(26) TF_R(6)  v0 += k0;  v1 += k1 + 3u;
  TF_R(17) TF_R(29) TF_R(16) TF_R(24) v0 += k1;  v1 += ks2 + 4u;
  TF_R(13) TF_R(15) TF_R(26) TF_R(6)  v0 += ks2; v1 += k0 + 5u;
#undef TF_R
  o0 = v0; o1 = v1;
}

__device__ __forceinline__ float drop_scale(unsigned ka, unsigned kb,
                                            unsigned pos) {
  unsigned o0, o1;
  threefry2x32(ka, kb, 0u, pos, o0, o1);
  return ((o0 ^ o1) >> 31) ? 0.0f : 2.0f;
}

__device__ __forceinline__ float bf2f(unsigned short u) {
  unsigned x = ((unsigned)u) << 16;
  float f;
  __builtin_memcpy(&f, &x, 4);
  return f;
}
__device__ __forceinline__ unsigned short f2bf(float f) {
  __hip_bfloat16 h = __float2bfloat16(f);
  unsigned short u;
  __builtin_memcpy(&u, &h, 2);
  return u;
}

// ---------------------------------------------------------------------------
// Fused init: zero both degree arrays + W1 transpose/convert + W2 split-
// precision transpose (hi+lo bf16, n padded to 48).
// ---------------------------------------------------------------------------
__global__ __launch_bounds__(256) void k_init(
    int* __restrict__ deg1, int n1, int* __restrict__ deg0, int n0,
    const float* __restrict__ W1, unsigned short* __restrict__ W1T,
    const float* __restrict__ W2, unsigned short* __restrict__ W2Th,
    unsigned short* __restrict__ W2Tl) {
  int i = blockIdx.x * 256 + threadIdx.x;
  if (i < n1) deg1[i] = 0;
  if (i < n0) deg0[i] = 0;
  if (i < 32768) {
    int n = i >> 7, k = i & 127;
    W1T[n * 128 + k] = f2bf(W1[k * 256 + n]);
  } else if (i < 32768 + 48 * 256) {
    int j = i - 32768;
    int n = j >> 8, k = j & 255;
    float w = (n < 47) ? W2[k * 47 + n] : 0.f;
    unsigned short hi = f2bf(w);
    float r = w - bf2f(hi);
    W2Th[n * 256 + k] = hi;
    W2Tl[n * 256 + k] = f2bf(r);
  }
}

// ---------------------------------------------------------------------------
// CSR build (both graphs in single launches): count, scan x2, fill
// ---------------------------------------------------------------------------
__global__ __launch_bounds__(256) void k_countm(
    const int* __restrict__ dst1, int* __restrict__ deg1, int E1,
    const int* __restrict__ dst0, int* __restrict__ deg0, int E0) {
  int e = blockIdx.x * 256 + threadIdx.x;
  if (e < E1) {
    atomicAdd(&deg1[dst1[e]], 1);
  } else {
    int e0 = e - E1;
    if (e0 < E0) atomicAdd(&deg0[dst0[e0]], 1);
  }
}

// pass 1: per-1024 chunk exclusive scan; two independent segments by block.
__global__ __launch_bounds__(256) void k_scan1m(
    const int* __restrict__ d1, int* __restrict__ o1, int* __restrict__ b1,
    int n1, int B1,
    const int* __restrict__ d0, int* __restrict__ o0, int* __restrict__ b0,
    int n0) {
  __shared__ int ls[256];
  const int* d; int* o; int* bs; int n; int blk;
  if ((int)blockIdx.x < B1) {
    d = d1; o = o1; bs = b1; n = n1; blk = blockIdx.x;
  } else {
    d = d0; o = o0; bs = b0; n = n0; blk = blockIdx.x - B1;
  }
  int t = threadIdx.x;
  int base = blk * 1024 + t * 4;
  int v[4], s = 0;
#pragma unroll
  for (int q = 0; q < 4; ++q) {
    int i = base + q;
    v[q] = (i < n) ? d[i] : 0;
    s += v[q];
  }
  ls[t] = s;
  __syncthreads();
  for (int off = 1; off < 256; off <<= 1) {
    int x = (t >= off) ? ls[t - off] : 0;
    __syncthreads();
    ls[t] += x;
    __syncthreads();
  }
  int run = ls[t] - s;
  if (t == 255) bs[blk] = ls[255];
#pragma unroll
  for (int q = 0; q < 4; ++q) {
    int i = base + q;
    if (i < n) o[i] = run;
    run += v[q];
  }
}

// pass 2+3 fused: each block reduces bs[0..blk) in LDS (blk <= ~108 < 256),
// adds to its chunk, and emits the mutable cursor copy woff[0..N).
__global__ __launch_bounds__(256) void k_scan23m(
    int* __restrict__ o1, int* __restrict__ w1, const int* __restrict__ bs1_,
    int n1, int B1,
    int* __restrict__ o0, int* __restrict__ w0, const int* __restrict__ bs0_,
    int n0) {
  __shared__ int ls[256];
  int* o; int* w; const int* bs; int n; int blk;
  if ((int)blockIdx.x < B1) {
    o = o1; w = w1; bs = bs1_; n = n1; blk = blockIdx.x;
  } else {
    o = o0; w = w0; bs = bs0_; n = n0; blk = blockIdx.x - B1;
  }
  int t = threadIdx.x;
  ls[t] = (t < blk) ? bs[t] : 0;
  __syncthreads();
#pragma unroll
  for (int off = 128; off > 0; off >>= 1) {
    if (t < off) ls[t] += ls[t + off];
    __syncthreads();
  }
  int add = ls[0];
  int base = blk * 1024 + t * 4;
#pragma unroll
  for (int q = 0; q < 4; ++q) {
    int i = base + q;
    if (i < n) {
      int v = o[i] + add;
      o[i] = v;
      if (i < n - 1) w[i] = v;   // cursor copy for fill (N entries)
    }
  }
}

// fill: csr[pos] = {r, sel[r]} ; cursor = atomic on woff (scanned copy)
__global__ __launch_bounds__(256) void k_fillm(
    const int* __restrict__ src1, const int* __restrict__ dst1,
    const int* __restrict__ s2, int* __restrict__ woff1,
    int2* __restrict__ csr1, int E1,
    const int* __restrict__ src0, const int* __restrict__ dst0,
    const int* __restrict__ s1, int* __restrict__ woff0,
    int2* __restrict__ csr0, int E0) {
  int e = blockIdx.x * 256 + threadIdx.x;
  if (e < E1) {
    int d = dst1[e];
    int pos = atomicAdd(&woff1[d], 1);
    int r = src1[e];
    csr1[pos] = make_int2(r, s2[r]);
  } else {
    int e0 = e - E1;
    if (e0 < E0) {
      int d = dst0[e0];
      int pos = atomicAdd(&woff0[d], 1);
      int r = src0[e0];
      csr0[pos] = make_int2(r, s1[r]);
    }
  }
}

// ---------------------------------------------------------------------------
// Merged aggregation d=128 (hop1 nodes 0..N1-1, hop0 nodes N1..Ntot-1).
// One wave per dst node. lane owns cols {2l, 2l+1}. x2 unroll for load ILP
// (accumulation order preserved -> bit-identical results).
// ---------------------------------------------------------------------------
__global__ __launch_bounds__(256) void k_agg128m(
    const float* __restrict__ feats,
    const int* __restrict__ off1, const int2* __restrict__ csr1,
    const int* __restrict__ sel1,
    const int* __restrict__ off0, const int2* __restrict__ csr0,
    const int* __restrict__ sel0,
    unsigned short* __restrict__ outbf, int N1, int Ntot,
    unsigned k1fa, unsigned k1fb, unsigned k1ha, unsigned k1hb,
    unsigned k0fa, unsigned k0fb, unsigned k0ha, unsigned k0hb) {
  int wave = (blockIdx.x * 256 + threadIdx.x) >> 6;
  int lane = threadIdx.x & 63;
  if (wave >= Ntot) return;
  const int* off; const int2* csr; const int* sel;
  unsigned kfa, kfb, kha, khb; int w;
  if (wave < N1) {
    off = off1; csr = csr1; sel = sel1;
    kfa = k1fa; kfb = k1fb; kha = k1ha; khb = k1hb; w = wave;
  } else {
    off = off0; csr = csr0; sel = sel0;
    kfa = k0fa; kfb = k0fb; kha = k0ha; khb = k0hb; w = wave - N1;
  }
  int beg = off[w], end = off[w + 1];
  float acc0 = 0.f, acc1 = 0.f;
  for (int base = beg; base < end; base += 64) {
    int idx = base + lane;
    int2 rg = make_int2(0, 0);
    if (idx < end) rg = csr[idx];
    int r_l = rg.x, g_l = rg.y;
    int cnt = min(64, end - base);
    int b = 0;
    for (; b + 2 <= cnt; b += 2) {
      int ra = __shfl(r_l, b),     ga = __shfl(g_l, b);
      int rb = __shfl(r_l, b + 1), gb = __shfl(g_l, b + 1);
      float2 fa = *(const float2*)(feats + (size_t)ga * 128 + lane * 2);
      float2 fb = *(const float2*)(feats + (size_t)gb * 128 + lane * 2);
      unsigned pa = (unsigned)ra * 128u + (unsigned)(lane * 2);
      unsigned pb = (unsigned)rb * 128u + (unsigned)(lane * 2);
      acc0 += fa.x * drop_scale(kfa, kfb, pa);
      acc1 += fa.y * drop_scale(kfa, kfb, pa + 1);
      acc0 += fb.x * drop_scale(kfa, kfb, pb);
      acc1 += fb.y * drop_scale(kfa, kfb, pb + 1);
    }
    if (b < cnt) {
      int r = __shfl(r_l, b), g = __shfl(g_l, b);
      float2 f = *(const float2*)(feats + (size_t)g * 128 + lane * 2);
      unsigned p = (unsigned)r * 128u + (unsigned)(lane * 2);
      acc0 += f.x * drop_scale(kfa, kfb, p);
      acc1 += f.y * drop_scale(kfa, kfb, p + 1);
    }
  }
  float deg = (float)(end - beg);
  float inv = deg > 0.f ? 1.0f / deg : 0.f;
  float n0 = acc0 * inv, n1 = acc1 * inv;
  float2 sf = *(const float2*)(feats + (size_t)sel[w] * 128 + lane * 2);
  unsigned ps = (unsigned)w * 128u + (unsigned)(lane * 2);
  float v0 = n0 + sf.x * drop_scale(kha, khb, ps);
  float v1 = n1 + sf.y * drop_scale(kha, khb, ps + 1);
  v0 = v0 > 0.f ? v0 : 0.f;
  v1 = v1 > 0.f ? v1 : 0.f;
  ushort2 u;
  u.x = f2bf(v0);
  u.y = f2bf(v1);
  *(ushort2*)(outbf + (size_t)wave * 128 + lane * 2) = u;
}

// ---------------------------------------------------------------------------
// Aggregation d=256 over bf16 rows, 2x column-split for occupancy:
// wave wid handles node w=wid>>1, column half h=wid&1; lane owns 2 cols
// c0 = h*128 + lane*2. RNG positions & accumulation order unchanged.
// ---------------------------------------------------------------------------
__global__ __launch_bounds__(256) void k_agg256(
    const unsigned short* __restrict__ X, const int* __restrict__ off,
    const int2* __restrict__ csr, const unsigned short* __restrict__ self,
    unsigned short* __restrict__ outbf, int N,
    unsigned kfa, unsigned kfb, unsigned kha, unsigned khb) {
  int wid = (blockIdx.x * 256 + threadIdx.x) >> 6;
  int lane = threadIdx.x & 63;
  if (wid >= 2 * N) return;
  int w = wid >> 1;
  int c0 = ((wid & 1) << 7) + lane * 2;
  int beg = off[w], end = off[w + 1];
  float a0 = 0.f, a1 = 0.f;
  for (int base = beg; base < end; base += 64) {
    int idx = base + lane;
    int r_l = 0;
    if (idx < end) r_l = csr[idx].x;
    int cnt = min(64, end - base);
    int b = 0;
    for (; b + 2 <= cnt; b += 2) {
      int ra = __shfl(r_l, b), rb = __shfl(r_l, b + 1);
      unsigned rawa = *(const unsigned*)(X + (size_t)ra * 256 + c0);
      unsigned rawb = *(const unsigned*)(X + (size_t)rb * 256 + c0);
      unsigned pa = (unsigned)ra * 256u + (unsigned)c0;
      unsigned pb = (unsigned)rb * 256u + (unsigned)c0;
      a0 += bf2f((unsigned short)rawa) * drop_scale(kfa, kfb, pa);
      a1 += bf2f((unsigned short)(rawa >> 16)) * drop_scale(kfa, kfb, pa + 1);
      a0 += bf2f((unsigned short)rawb) * drop_scale(kfa, kfb, pb);
      a1 += bf2f((unsigned short)(rawb >> 16)) * drop_scale(kfa, kfb, pb + 1);
    }
    if (b < cnt) {
      int r = __shfl(r_l, b);
      unsigned raw = *(const unsigned*)(X + (size_t)r * 256 + c0);
      unsigned p = (unsigned)r * 256u + (unsigned)c0;
      a0 += bf2f((unsigned short)raw) * drop_scale(kfa, kfb, p);
      a1 += bf2f((unsigned short)(raw >> 16)) * drop_scale(kfa, kfb, p + 1);
    }
  }
  float deg = (float)(end - beg);
  float inv = deg > 0.f ? 1.0f / deg : 0.f;
  unsigned sraw = *(const unsigned*)(self + (size_t)w * 256 + c0);
  unsigned ps = (unsigned)w * 256u + (unsigned)c0;
  float v0 = a0 * inv + bf2f((unsigned short)sraw) * drop_scale(kha, khb, ps);
  float v1 = a1 * inv +
             bf2f((unsigned short)(sraw >> 16)) * drop_scale(kha, khb, ps + 1);
  v0 = v0 > 0.f ? v0 : 0.f;
  v1 = v1 > 0.f ? v1 : 0.f;
  ushort2 u;
  u.x = f2bf(v0);
  u.y = f2bf(v1);
  *(ushort2*)(outbf + (size_t)w * 256 + c0) = u;
}

// ---------------------------------------------------------------------------
// GEMM1: C[M,256](bf16) = A[M,128](bf16) @ W1 + b1, via MFMA 16x16x32 bf16.
// grid (ceil(M/128), 2). Block 256 = 4 waves, each wave a 64x64 C sub-tile.
// ---------------------------------------------------------------------------
__global__ __launch_bounds__(256) void k_gemm1(
    const unsigned short* __restrict__ A, const unsigned short* __restrict__ W1T,
    const float* __restrict__ bias, unsigned short* __restrict__ C, int M) {
  __shared__ unsigned short As[128 * 72];
  __shared__ unsigned short Bs[128 * 72];
  const int t = threadIdx.x;
  const int r0 = blockIdx.x * 128, n0 = blockIdx.y * 128;
  const int wv = t >> 6, lane = t & 63;
  const int mb = (wv >> 1) * 64, nb = (wv & 1) * 64;
  const int qm = lane & 15, quad = lane >> 4;
  v4f acc[4][4];
#pragma unroll
  for (int i = 0; i < 4; ++i)
#pragma unroll
    for (int j = 0; j < 4; ++j) acc[i][j] = (v4f){0.f, 0.f, 0.f, 0.f};

  for (int kt = 0; kt < 128; kt += 64) {
#pragma unroll
    for (int it = 0; it < 4; ++it) {
      int i = t + it * 256;            // 0..1023
      int r = i >> 3, c = i & 7;
      uint4 v = make_uint4(0, 0, 0, 0);
      int gr = r0 + r;
      if (gr < M) v = ((const uint4*)A)[(size_t)gr * 16 + (kt >> 3) + c];
      *(uint4*)&As[r * 72 + c * 8] = v;
    }
#pragma unroll
    for (int it = 0; it < 4; ++it) {
      int i = t + it * 256;
      int n = i >> 3, c = i & 7;
      uint4 v = ((const uint4*)W1T)[(size_t)(n0 + n) * 16 + (kt >> 3) + c];
      *(uint4*)&Bs[n * 72 + c * 8] = v;
    }
    __syncthreads();
#pragma unroll
    for (int kk = 0; kk < 64; kk += 32) {
      v8s af[4], bf_[4];
#pragma unroll
      for (int i = 0; i < 4; ++i)
        af[i] = *(const v8s*)&As[(mb + i * 16 + qm) * 72 + kk + quad * 8];
#pragma unroll
      for (int j = 0; j < 4; ++j)
        bf_[j] = *(const v8s*)&Bs[(nb + j * 16 + qm) * 72 + kk + quad * 8];
#pragma unroll
      for (int i = 0; i < 4; ++i)
#pragma unroll
        for (int j = 0; j < 4; ++j)
          acc[i][j] = __builtin_amdgcn_mfma_f32_16x16x32_bf16(
              af[i], bf_[j], acc[i][j], 0, 0, 0);
    }
    __syncthreads();
  }
  // epilogue: D col = lane&15, row = quad*4 + reg (m89-verified)
  const int col_base = n0 + nb + qm;
  float bj[4];
#pragma unroll
  for (int j = 0; j < 4; ++j) bj[j] = bias[col_base + j * 16];
#pragma unroll
  for (int i = 0; i < 4; ++i) {
    int row = r0 + mb + i * 16 + quad * 4;
#pragma unroll
    for (int reg = 0; reg < 4; ++reg) {
      int rr = row + reg;
      if (rr < M) {
#pragma unroll
        for (int j = 0; j < 4; ++j)
          C[(size_t)rr * 256 + col_base + j * 16] = f2bf(acc[i][j][reg] + bj[j]);
      }
    }
  }
}

// ---------------------------------------------------------------------------
// GEMM2 (MFMA): out[M,47](f32) = A[M,256](bf16) @ (W2hi+W2lo) + b2.
// Block = 64 rows (4 waves x 16 rows); N padded to 48 (3 col-tiles).
// Split-precision W2 keeps f32-level weight accuracy.
// ---------------------------------------------------------------------------
__global__ __launch_bounds__(256) void k_gemm2(
    const unsigned short* __restrict__ A, const unsigned short* __restrict__ Bh,
    const unsigned short* __restrict__ Bl, const float* __restrict__ b2,
    float* __restrict__ out, int M) {
  const int t = threadIdx.x;
  const int wv = t >> 6, lane = t & 63;
  const int qm = lane & 15, quad = lane >> 4;
  const int rw = blockIdx.x * 64 + wv * 16;
  v4f acc[3];
#pragma unroll
  for (int j = 0; j < 3; ++j) acc[j] = (v4f){0.f, 0.f, 0.f, 0.f};
  int arow = rw + qm;
  if (arow >= M) arow = M - 1;                 // clamp; masked at store
  const unsigned short* Ar = A + (size_t)arow * 256;
#pragma unroll
  for (int kk = 0; kk < 256; kk += 32) {
    v8s af = *(const v8s*)&Ar[kk + quad * 8];
#pragma unroll
    for (int j = 0; j < 3; ++j) {
      v8s bh = *(const v8s*)&Bh[(size_t)(j * 16 + qm) * 256 + kk + quad * 8];
      v8s bl = *(const v8s*)&Bl[(size_t)(j * 16 + qm) * 256 + kk + quad * 8];
      acc[j] = __builtin_amdgcn_mfma_f32_16x16x32_bf16(af, bh, acc[j], 0, 0, 0);
      acc[j] = __builtin_amdgcn_mfma_f32_16x16x32_bf16(af, bl, acc[j], 0, 0, 0);
    }
  }
#pragma unroll
  for (int j = 0; j < 3; ++j) {
    int col = j * 16 + qm;
    if (col >= 47) continue;
    float bb = b2[col];
#pragma unroll
    for (int reg = 0; reg < 4; ++reg) {
      int row = rw + quad * 4 + reg;
      if (row < M) out[(size_t)row * 47 + col] = acc[j][reg] + bb;
    }
  }
}

// ---------------------------------------------------------------------------
// Launch
// ---------------------------------------------------------------------------
static inline size_t alignup(size_t x) { return (x + 255) & ~(size_t)255; }

extern "C" void kernel_launch(void* const* d_in, const int* in_sizes, int n_in,
                              void* d_out, int out_size, void* d_ws,
                              size_t ws_size, hipStream_t stream) {
  const float* features = (const float*)d_in[0];
  const int* s0   = (const int*)d_in[1];
  const int* s1   = (const int*)d_in[2];
  const int* s2   = (const int*)d_in[3];
  const int* src0 = (const int*)d_in[4];
  const int* dst0 = (const int*)d_in[5];
  const int* src1 = (const int*)d_in[6];
  const int* dst1 = (const int*)d_in[7];
  const float* W1 = (const float*)d_in[8];
  const float* b1 = (const float*)d_in[9];
  const float* W2 = (const float*)d_in[10];
  const float* b2 = (const float*)d_in[11];
  float* out = (float*)d_out;

  const int N0 = in_sizes[1], N1 = in_sizes[2];
  const int E0 = in_sizes[4], E1 = in_sizes[6];
  const int Ntot = N1 + N0;
  const int Etot = E1 + E0;

  // ---- key derivation (partitionable; verified round 1) ----
  unsigned dk[3][2], kfs[3][2], khs[3][2];
  for (int i = 0; i < 3; ++i)
    threefry2x32(0u, 42u, 0u, (unsigned)i, dk[i][0], dk[i][1]);
  for (int i = 0; i < 3; ++i) {
    threefry2x32(dk[i][0], dk[i][1], 0u, 0u, kfs[i][0], kfs[i][1]);
    threefry2x32(dk[i][0], dk[i][1], 0u, 1u, khs[i][0], khs[i][1]);
  }

  // ---- workspace layout ----
  char* p = (char*)d_ws;
  auto take = [&](size_t bytes) {
    char* r = p;
    p += alignup(bytes);
    return r;
  };
  // a_all rows: [0,N1) = hop1 agg out; [N1,Ntot) = hop0 agg out.
  unsigned short* a_all = (unsigned short*)take((size_t)Ntot * 128 * 2);
  unsigned short* n_all = (unsigned short*)take((size_t)Ntot * 256 * 2);
  unsigned short* a2bf  = (unsigned short*)take((size_t)N0 * 256 * 2);
  unsigned short* w1t   = (unsigned short*)take(256 * 128 * 2);
  unsigned short* w2th  = (unsigned short*)take(48 * 256 * 2);
  unsigned short* w2tl  = (unsigned short*)take(48 * 256 * 2);
  int* off1  = (int*)take((size_t)(N1 + 2) * 4);
  int* woff1 = (int*)take((size_t)N1 * 4);
  int* deg1  = (int*)take((size_t)(N1 + 2) * 4);
  int* off0  = (int*)take((size_t)(N0 + 2) * 4);
  int* woff0 = (int*)take((size_t)N0 * 4);
  int* deg0  = (int*)take((size_t)(N0 + 2) * 4);
  int* bs1   = (int*)take(1024 * 4);
  int* bs0   = (int*)take(1024 * 4);
  int2* csr1 = (int2*)take((size_t)E1 * 8);
  int2* csr0 = (int2*)take((size_t)E0 * 8);

  {
    int span = N1 + 2;
    if (N0 + 2 > span) span = N0 + 2;
    if (32768 + 48 * 256 > span) span = 32768 + 48 * 256;
    k_init<<<(span + 255) / 256, 256, 0, stream>>>(deg1, N1 + 2, deg0, N0 + 2,
                                                   W1, w1t, W2, w2th, w2tl);
  }
  k_countm<<<(Etot + 255) / 256, 256, 0, stream>>>(dst1, deg1, E1, dst0, deg0,
                                                   E0);

  const int n1s = N1 + 1, B1 = (n1s + 1023) / 1024;
  const int n0s = N0 + 1, B0 = (n0s + 1023) / 1024;
  k_scan1m<<<B1 + B0, 256, 0, stream>>>(deg1, off1, bs1, n1s, B1,
                                        deg0, off0, bs0, n0s);
  k_scan23m<<<B1 + B0, 256, 0, stream>>>(off1, woff1, bs1, n1s, B1,
                                         off0, woff0, bs0, n0s);

  k_fillm<<<(Etot + 255) / 256, 256, 0, stream>>>(
      src1, dst1, s2, woff1, csr1, E1,
      src0, dst0, s1, woff0, csr0, E0);

  // layer 0, both hops in one launch: rows [0,N1) hop1, [N1,Ntot) hop0
  k_agg128m<<<(Ntot + 3) / 4, 256, 0, stream>>>(
      features, off1, csr1, s1, off0, csr0, s0, a_all, N1, Ntot,
      kfs[1][0], kfs[1][1], khs[1][0], khs[1][1],
      kfs[0][0], kfs[0][1], khs[0][0], khs[0][1]);
  {
    dim3 g((Ntot + 127) / 128, 2);
    k_gemm1<<<g, 256, 0, stream>>>(a_all, w1t, b1, n_all, Ntot);
  }

  // layer 1: a = agg(graph0, n1, n0) ; out = a@W2+b2
  k_agg256<<<(2 * N0 + 3) / 4, 256, 0, stream>>>(
      n_all, off0, csr0, n_all + (size_t)N1 * 256, a2bf, N0,
      kfs[2][0], kfs[2][1], khs[2][0], khs[2][1]);
  k_gemm2<<<(N0 + 63) / 64, 256, 0, stream>>>(a2bf, w2th, w2tl, b2, out, N0);
}

// Round 3
// 1151.973 us; speedup vs baseline: 1.0851x; 1.0041x over previous
//
#include <hip/hip_runtime.h>
#include <hip/hip_bf16.h>

typedef short v8s __attribute__((ext_vector_type(8)));
typedef float v4f __attribute__((ext_vector_type(4)));

// ---------------------------------------------------------------------------
// JAX threefry2x32 replication (partitionable mode verified in round 1).
// keep  <=>  (o0^o1) < 2^31   for p = 0.5.
// ---------------------------------------------------------------------------
__host__ __device__ __forceinline__ unsigned rotl32(unsigned x, int d) {
  return (x << d) | (x >> (32 - d));
}

__host__ __device__ __forceinline__ void threefry2x32(
    unsigned k0, unsigned k1, unsigned x0, unsigned x1,
    unsigned& o0, unsigned& o1) {
  unsigned ks2 = k0 ^ k1 ^ 0x1BD11BDAu;
  unsigned v0 = x0 + k0, v1 = x1 + k1;
#define TF_R(r) { v0 += v1; v1 = rotl32(v1, (r)); v1 ^= v0; }
  TF_R(13) TF_R(15) TF_R(26) TF_R(6)  v0 += k1;  v1 += ks2 + 1u;
  TF_R(17) TF_R(29) TF_R(16) TF_R(24) v0 += ks2; v1 += k0 + 2u;
  TF_R(13) TF_R(15) TF_R(26) TF_R(6)  v0 += k0;  v1 += k1 + 3u;
  TF_R(17) TF_R(29) TF_R(16) TF_R(24) v0 += k1;  v1 += ks2 + 4u;
  TF_R(13) TF_R(15) TF_R(26) TF_R(6)  v0 += ks2; v1 += k0 + 5u;
#undef TF_R
  o0 = v0; o1 = v1;
}

__device__ __forceinline__ float drop_scale(unsigned ka, unsigned kb,
                                            unsigned pos) {
  unsigned o0, o1;
  threefry2x32(ka, kb, 0u, pos, o0, o1);
  return ((o0 ^ o1) >> 31) ? 0.0f : 2.0f;
}

__device__ __forceinline__ float bf2f(unsigned short u) {
  unsigned x = ((unsigned)u) << 16;
  float f;
  __builtin_memcpy(&f, &x, 4);
  return f;
}
__device__ __forceinline__ unsigned short f2bf(float f) {
  __hip_bfloat16 h = __float2bfloat16(f);
  unsigned short u;
  __builtin_memcpy(&u, &h, 2);
  return u;
}

// ---------------------------------------------------------------------------
// Fused init: zero degree arrays + scan flags + W1 transpose/convert + W2
// split-precision transpose (hi+lo bf16, n padded to 48).
// ---------------------------------------------------------------------------
__global__ __launch_bounds__(256) void k_init(
    int* __restrict__ deg1, int n1, int* __restrict__ deg0, int n0,
    unsigned* __restrict__ fl1, unsigned* __restrict__ fl0,
    const float* __restrict__ W1, unsigned short* __restrict__ W1T,
    const float* __restrict__ W2, unsigned short* __restrict__ W2Th,
    unsigned short* __restrict__ W2Tl) {
  int i = blockIdx.x * 256 + threadIdx.x;
  if (i < n1) deg1[i] = 0;
  if (i < n0) deg0[i] = 0;
  if (i < 1024) { fl1[i] = 0u; fl0[i] = 0u; }
  if (i < 32768) {
    int n = i >> 7, k = i & 127;
    W1T[n * 128 + k] = f2bf(W1[k * 256 + n]);
  } else if (i < 32768 + 48 * 256) {
    int j = i - 32768;
    int n = j >> 8, k = j & 255;
    float w = (n < 47) ? W2[k * 47 + n] : 0.f;
    unsigned short hi = f2bf(w);
    float r = w - bf2f(hi);
    W2Th[n * 256 + k] = hi;
    W2Tl[n * 256 + k] = f2bf(r);
  }
}

// ---------------------------------------------------------------------------
// CSR build: count, single-pass lookback scan, fill
// ---------------------------------------------------------------------------
__global__ __launch_bounds__(256) void k_countm(
    const int* __restrict__ dst1, int* __restrict__ deg1, int E1,
    const int* __restrict__ dst0, int* __restrict__ deg0, int E0) {
  int e = blockIdx.x * 256 + threadIdx.x;
  if (e < E1) {
    atomicAdd(&deg1[dst1[e]], 1);
  } else {
    int e0 = e - E1;
    if (e0 < E0) atomicAdd(&deg0[dst0[e0]], 1);
  }
}

// Single-pass exclusive scan with block-sum lookback. Two segments by block.
// Safe: B1+B0 <= ~108 blocks, all co-resident (<< 2048 capacity); every block
// publishes its own sum BEFORE polling predecessors -> no circular wait.
__global__ __launch_bounds__(256) void k_scanlb(
    const int* __restrict__ d1, int* __restrict__ o1, int* __restrict__ w1,
    unsigned* __restrict__ fl1, int n1, int B1,
    const int* __restrict__ d0, int* __restrict__ o0, int* __restrict__ w0,
    unsigned* __restrict__ fl0, int n0) {
  __shared__ int ls[256];
  const int* d; int* o; int* w; unsigned* fl; int n; int blk;
  if ((int)blockIdx.x < B1) {
    d = d1; o = o1; w = w1; fl = fl1; n = n1; blk = blockIdx.x;
  } else {
    d = d0; o = o0; w = w0; fl = fl0; n = n0; blk = blockIdx.x - B1;
  }
  int t = threadIdx.x;
  int base = blk * 1024 + t * 4;
  int v[4], s = 0;
#pragma unroll
  for (int q = 0; q < 4; ++q) {
    int i = base + q;
    v[q] = (i < n) ? d[i] : 0;
    s += v[q];
  }
  ls[t] = s;
  __syncthreads();
  for (int off = 1; off < 256; off <<= 1) {
    int x = (t >= off) ? ls[t - off] : 0;
    __syncthreads();
    ls[t] += x;
    __syncthreads();
  }
  int run = ls[t] - s;          // exclusive prefix within chunk
  int tot = ls[255];            // chunk total (valid for all threads)
  if (t == 0)
    __hip_atomic_store(&fl[blk], 0x80000000u | (unsigned)tot,
                       __ATOMIC_RELEASE, __HIP_MEMORY_SCOPE_AGENT);
  // lookback: thread t polls chunk t's published sum (t < blk)
  unsigned mine = 0;
  if (t < blk) {
    unsigned x;
    do {
      x = __hip_atomic_load(&fl[t], __ATOMIC_ACQUIRE, __HIP_MEMORY_SCOPE_AGENT);
    } while (!(x >> 31));
    mine = x & 0x7fffffffu;
  }
  __syncthreads();              // ls free for reuse
  ls[t] = (int)mine;
  __syncthreads();
#pragma unroll
  for (int off = 128; off > 0; off >>= 1) {
    if (t < off) ls[t] += ls[t + off];
    __syncthreads();
  }
  int add = ls[0];
#pragma unroll
  for (int q = 0; q < 4; ++q) {
    int i = base + q;
    if (i < n) {
      int vv = run + add;
      o[i] = vv;
      if (i < n - 1) w[i] = vv;   // mutable cursor copy for fill (N entries)
    }
    run += v[q];
  }
}

// fill: csr[pos] = {r, sel[r]} ; cursor = atomic on woff (scanned copy)
__global__ __launch_bounds__(256) void k_fillm(
    const int* __restrict__ src1, const int* __restrict__ dst1,
    const int* __restrict__ s2, int* __restrict__ woff1,
    int2* __restrict__ csr1, int E1,
    const int* __restrict__ src0, const int* __restrict__ dst0,
    const int* __restrict__ s1, int* __restrict__ woff0,
    int2* __restrict__ csr0, int E0) {
  int e = blockIdx.x * 256 + threadIdx.x;
  if (e < E1) {
    int d = dst1[e];
    int pos = atomicAdd(&woff1[d], 1);
    int r = src1[e];
    csr1[pos] = make_int2(r, s2[r]);
  } else {
    int e0 = e - E1;
    if (e0 < E0) {
      int d = dst0[e0];
      int pos = atomicAdd(&woff0[d], 1);
      int r = src0[e0];
      csr0[pos] = make_int2(r, s1[r]);
    }
  }
}

// ---------------------------------------------------------------------------
// Merged aggregation d=128 (hop1 nodes 0..N1-1, hop0 nodes N1..Ntot-1).
// One wave per dst node. lane owns cols {2l, 2l+1}. Broadcasts carry
// pre-multiplied offsets (r*128, g*128). x2 unroll; order bit-identical.
// ---------------------------------------------------------------------------
__global__ __launch_bounds__(256) void k_agg128m(
    const float* __restrict__ feats,
    const int* __restrict__ off1, const int2* __restrict__ csr1,
    const int* __restrict__ sel1,
    const int* __restrict__ off0, const int2* __restrict__ csr0,
    const int* __restrict__ sel0,
    unsigned short* __restrict__ outbf, int N1, int Ntot,
    unsigned k1fa, unsigned k1fb, unsigned k1ha, unsigned k1hb,
    unsigned k0fa, unsigned k0fb, unsigned k0ha, unsigned k0hb) {
  int wave = (blockIdx.x * 256 + threadIdx.x) >> 6;
  int lane = threadIdx.x & 63;
  if (wave >= Ntot) return;
  const int* off; const int2* csr; const int* sel;
  unsigned kfa, kfb, kha, khb; int w;
  if (wave < N1) {
    off = off1; csr = csr1; sel = sel1;
    kfa = k1fa; kfb = k1fb; kha = k1ha; khb = k1hb; w = wave;
  } else {
    off = off0; csr = csr0; sel = sel0;
    kfa = k0fa; kfb = k0fb; kha = k0ha; khb = k0hb; w = wave - N1;
  }
  const unsigned ll2 = (unsigned)(lane * 2);
  int beg = off[w], end = off[w + 1];
  float acc0 = 0.f, acc1 = 0.f;
  for (int base = beg; base < end; base += 64) {
    int idx = base + lane;
    int2 rg = make_int2(0, 0);
    if (idx < end) rg = csr[idx];
    unsigned pr_l = (unsigned)rg.x * 128u;   // RNG row base
    unsigned pg_l = (unsigned)rg.y * 128u;   // feature row base (elements)
    int cnt = min(64, end - base);
    int b = 0;
    for (; b + 2 <= cnt; b += 2) {
      unsigned pra = __shfl(pr_l, b),     pga = __shfl(pg_l, b);
      unsigned prb = __shfl(pr_l, b + 1), pgb = __shfl(pg_l, b + 1);
      float2 fa = *(const float2*)(feats + (size_t)pga + ll2);
      float2 fb = *(const float2*)(feats + (size_t)pgb + ll2);
      acc0 += fa.x * drop_scale(kfa, kfb, pra + ll2);
      acc1 += fa.y * drop_scale(kfa, kfb, pra + ll2 + 1);
      acc0 += fb.x * drop_scale(kfa, kfb, prb + ll2);
      acc1 += fb.y * drop_scale(kfa, kfb, prb + ll2 + 1);
    }
    if (b < cnt) {
      unsigned pr = __shfl(pr_l, b), pg = __shfl(pg_l, b);
      float2 f = *(const float2*)(feats + (size_t)pg + ll2);
      acc0 += f.x * drop_scale(kfa, kfb, pr + ll2);
      acc1 += f.y * drop_scale(kfa, kfb, pr + ll2 + 1);
    }
  }
  float deg = (float)(end - beg);
  float inv = deg > 0.f ? 1.0f / deg : 0.f;
  float n0 = acc0 * inv, n1 = acc1 * inv;
  float2 sf = *(const float2*)(feats + (size_t)sel[w] * 128 + ll2);
  unsigned ps = (unsigned)w * 128u + ll2;
  float v0 = n0 + sf.x * drop_scale(kha, khb, ps);
  float v1 = n1 + sf.y * drop_scale(kha, khb, ps + 1);
  v0 = v0 > 0.f ? v0 : 0.f;
  v1 = v1 > 0.f ? v1 : 0.f;
  ushort2 u;
  u.x = f2bf(v0);
  u.y = f2bf(v1);
  *(ushort2*)(outbf + (size_t)wave * 128 + ll2) = u;
}

// ---------------------------------------------------------------------------
// Aggregation d=256 over bf16 rows, 4x column-split for latency hiding:
// wave wid handles node w=wid>>2, column quarter q=wid&3; lane owns ONE col
// c0 = q*64 + lane. RNG positions & per-column accumulation order unchanged.
// ---------------------------------------------------------------------------
__global__ __launch_bounds__(256) void k_agg256(
    const unsigned short* __restrict__ X, const int* __restrict__ off,
    const int2* __restrict__ csr, const unsigned short* __restrict__ self,
    unsigned short* __restrict__ outbf, int N,
    unsigned kfa, unsigned kfb, unsigned kha, unsigned khb) {
  int wid = (blockIdx.x * 256 + threadIdx.x) >> 6;
  int lane = threadIdx.x & 63;
  if (wid >= 4 * N) return;
  int w = wid >> 2;
  unsigned c0 = (unsigned)(((wid & 3) << 6) + lane);
  int beg = off[w], end = off[w + 1];
  float a0 = 0.f;
  for (int base = beg; base < end; base += 64) {
    int idx = base + lane;
    unsigned p_l = 0;
    if (idx < end) p_l = (unsigned)csr[idx].x * 256u;
    int cnt = min(64, end - base);
    int b = 0;
    for (; b + 2 <= cnt; b += 2) {
      unsigned pa = __shfl(p_l, b), pb = __shfl(p_l, b + 1);
      float fa = bf2f(X[(size_t)pa + c0]);
      float fb = bf2f(X[(size_t)pb + c0]);
      a0 += fa * drop_scale(kfa, kfb, pa + c0);
      a0 += fb * drop_scale(kfa, kfb, pb + c0);
    }
    if (b < cnt) {
      unsigned p = __shfl(p_l, b);
      a0 += bf2f(X[(size_t)p + c0]) * drop_scale(kfa, kfb, p + c0);
    }
  }
  float deg = (float)(end - beg);
  float inv = deg > 0.f ? 1.0f / deg : 0.f;
  unsigned ps = (unsigned)w * 256u + c0;
  float v = a0 * inv +
            bf2f(self[(size_t)w * 256 + c0]) * drop_scale(kha, khb, ps);
  v = v > 0.f ? v : 0.f;
  outbf[(size_t)w * 256 + c0] = f2bf(v);
}

// ---------------------------------------------------------------------------
// GEMM1: C[M,256](bf16) = A[M,128](bf16) @ W1 + b1, via MFMA 16x16x32 bf16.
// grid (ceil(M/128), 2). Block 256 = 4 waves, each wave a 64x64 C sub-tile.
// ---------------------------------------------------------------------------
__global__ __launch_bounds__(256) void k_gemm1(
    const unsigned short* __restrict__ A, const unsigned short* __restrict__ W1T,
    const float* __restrict__ bias, unsigned short* __restrict__ C, int M) {
  __shared__ unsigned short As[128 * 72];
  __shared__ unsigned short Bs[128 * 72];
  const int t = threadIdx.x;
  const int r0 = blockIdx.x * 128, n0 = blockIdx.y * 128;
  const int wv = t >> 6, lane = t & 63;
  const int mb = (wv >> 1) * 64, nb = (wv & 1) * 64;
  const int qm = lane & 15, quad = lane >> 4;
  v4f acc[4][4];
#pragma unroll
  for (int i = 0; i < 4; ++i)
#pragma unroll
    for (int j = 0; j < 4; ++j) acc[i][j] = (v4f){0.f, 0.f, 0.f, 0.f};

  for (int kt = 0; kt < 128; kt += 64) {
#pragma unroll
    for (int it = 0; it < 4; ++it) {
      int i = t + it * 256;            // 0..1023
      int r = i >> 3, c = i & 7;
      uint4 v = make_uint4(0, 0, 0, 0);
      int gr = r0 + r;
      if (gr < M) v = ((const uint4*)A)[(size_t)gr * 16 + (kt >> 3) + c];
      *(uint4*)&As[r * 72 + c * 8] = v;
    }
#pragma unroll
    for (int it = 0; it < 4; ++it) {
      int i = t + it * 256;
      int n = i >> 3, c = i & 7;
      uint4 v = ((const uint4*)W1T)[(size_t)(n0 + n) * 16 + (kt >> 3) + c];
      *(uint4*)&Bs[n * 72 + c * 8] = v;
    }
    __syncthreads();
#pragma unroll
    for (int kk = 0; kk < 64; kk += 32) {
      v8s af[4], bf_[4];
#pragma unroll
      for (int i = 0; i < 4; ++i)
        af[i] = *(const v8s*)&As[(mb + i * 16 + qm) * 72 + kk + quad * 8];
#pragma unroll
      for (int j = 0; j < 4; ++j)
        bf_[j] = *(const v8s*)&Bs[(nb + j * 16 + qm) * 72 + kk + quad * 8];
#pragma unroll
      for (int i = 0; i < 4; ++i)
#pragma unroll
        for (int j = 0; j < 4; ++j)
          acc[i][j] = __builtin_amdgcn_mfma_f32_16x16x32_bf16(
              af[i], bf_[j], acc[i][j], 0, 0, 0);
    }
    __syncthreads();
  }
  // epilogue: D col = lane&15, row = quad*4 + reg (m89-verified)
  const int col_base = n0 + nb + qm;
  float bj[4];
#pragma unroll
  for (int j = 0; j < 4; ++j) bj[j] = bias[col_base + j * 16];
#pragma unroll
  for (int i = 0; i < 4; ++i) {
    int row = r0 + mb + i * 16 + quad * 4;
#pragma unroll
    for (int reg = 0; reg < 4; ++reg) {
      int rr = row + reg;
      if (rr < M) {
#pragma unroll
        for (int j = 0; j < 4; ++j)
          C[(size_t)rr * 256 + col_base + j * 16] = f2bf(acc[i][j][reg] + bj[j]);
      }
    }
  }
}

// ---------------------------------------------------------------------------
// GEMM2 (MFMA): out[M,47](f32) = A[M,256](bf16) @ (W2hi+W2lo) + b2.
// Block = 64 rows (4 waves x 16 rows); N padded to 48 (3 col-tiles).
// Split-precision W2 keeps f32-level weight accuracy.
// ---------------------------------------------------------------------------
__global__ __launch_bounds__(256) void k_gemm2(
    const unsigned short* __restrict__ A, const unsigned short* __restrict__ Bh,
    const unsigned short* __restrict__ Bl, const float* __restrict__ b2,
    float* __restrict__ out, int M) {
  const int t = threadIdx.x;
  const int wv = t >> 6, lane = t & 63;
  const int qm = lane & 15, quad = lane >> 4;
  const int rw = blockIdx.x * 64 + wv * 16;
  v4f acc[3];
#pragma unroll
  for (int j = 0; j < 3; ++j) acc[j] = (v4f){0.f, 0.f, 0.f, 0.f};
  int arow = rw + qm;
  if (arow >= M) arow = M - 1;                 // clamp; masked at store
  const unsigned short* Ar = A + (size_t)arow * 256;
#pragma unroll
  for (int kk = 0; kk < 256; kk += 32) {
    v8s af = *(const v8s*)&Ar[kk + quad * 8];
#pragma unroll
    for (int j = 0; j < 3; ++j) {
      v8s bh = *(const v8s*)&Bh[(size_t)(j * 16 + qm) * 256 + kk + quad * 8];
      v8s bl = *(const v8s*)&Bl[(size_t)(j * 16 + qm) * 256 + kk + quad * 8];
      acc[j] = __builtin_amdgcn_mfma_f32_16x16x32_bf16(af, bh, acc[j], 0, 0, 0);
      acc[j] = __builtin_amdgcn_mfma_f32_16x16x32_bf16(af, bl, acc[j], 0, 0, 0);
    }
  }
#pragma unroll
  for (int j = 0; j < 3; ++j) {
    int col = j * 16 + qm;
    if (col >= 47) continue;
    float bb = b2[col];
#pragma unroll
    for (int reg = 0; reg < 4; ++reg) {
      int row = rw + quad * 4 + reg;
      if (row < M) out[(size_t)row * 47 + col] = acc[j][reg] + bb;
    }
  }
}

// ---------------------------------------------------------------------------
// Launch
// ---------------------------------------------------------------------------
static inline size_t alignup(size_t x) { return (x + 255) & ~(size_t)255; }

extern "C" void kernel_launch(void* const* d_in, const int* in_sizes, int n_in,
                              void* d_out, int out_size, void* d_ws,
                              size_t ws_size, hipStream_t stream) {
  const float* features = (const float*)d_in[0];
  const int* s0   = (const int*)d_in[1];
  const int* s1   = (const int*)d_in[2];
  const int* s2   = (const int*)d_in[3];
  const int* src0 = (const int*)d_in[4];
  const int* dst0 = (const int*)d_in[5];
  const int* src1 = (const int*)d_in[6];
  const int* dst1 = (const int*)d_in[7];
  const float* W1 = (const float*)d_in[8];
  const float* b1 = (const float*)d_in[9];
  const float* W2 = (const float*)d_in[10];
  const float* b2 = (const float*)d_in[11];
  float* out = (float*)d_out;

  const int N0 = in_sizes[1], N1 = in_sizes[2];
  const int E0 = in_sizes[4], E1 = in_sizes[6];
  const int Ntot = N1 + N0;
  const int Etot = E1 + E0;

  // ---- key derivation (partitionable; verified round 1) ----
  unsigned dk[3][2], kfs[3][2], khs[3][2];
  for (int i = 0; i < 3; ++i)
    threefry2x32(0u, 42u, 0u, (unsigned)i, dk[i][0], dk[i][1]);
  for (int i = 0; i < 3; ++i) {
    threefry2x32(dk[i][0], dk[i][1], 0u, 0u, kfs[i][0], kfs[i][1]);
    threefry2x32(dk[i][0], dk[i][1], 0u, 1u, khs[i][0], khs[i][1]);
  }

  // ---- workspace layout ----
  char* p = (char*)d_ws;
  auto take = [&](size_t bytes) {
    char* r = p;
    p += alignup(bytes);
    return r;
  };
  // a_all rows: [0,N1) = hop1 agg out; [N1,Ntot) = hop0 agg out.
  unsigned short* a_all = (unsigned short*)take((size_t)Ntot * 128 * 2);
  unsigned short* n_all = (unsigned short*)take((size_t)Ntot * 256 * 2);
  unsigned short* a2bf  = (unsigned short*)take((size_t)N0 * 256 * 2);
  unsigned short* w1t   = (unsigned short*)take(256 * 128 * 2);
  unsigned short* w2th  = (unsigned short*)take(48 * 256 * 2);
  unsigned short* w2tl  = (unsigned short*)take(48 * 256 * 2);
  int* off1  = (int*)take((size_t)(N1 + 2) * 4);
  int* woff1 = (int*)take((size_t)N1 * 4);
  int* deg1  = (int*)take((size_t)(N1 + 2) * 4);
  int* off0  = (int*)take((size_t)(N0 + 2) * 4);
  int* woff0 = (int*)take((size_t)N0 * 4);
  int* deg0  = (int*)take((size_t)(N0 + 2) * 4);
  unsigned* fl1 = (unsigned*)take(1024 * 4);
  unsigned* fl0 = (unsigned*)take(1024 * 4);
  int2* csr1 = (int2*)take((size_t)E1 * 8);
  int2* csr0 = (int2*)take((size_t)E0 * 8);

  {
    int span = N1 + 2;
    if (N0 + 2 > span) span = N0 + 2;
    if (32768 + 48 * 256 > span) span = 32768 + 48 * 256;
    k_init<<<(span + 255) / 256, 256, 0, stream>>>(
        deg1, N1 + 2, deg0, N0 + 2, fl1, fl0, W1, w1t, W2, w2th, w2tl);
  }
  k_countm<<<(Etot + 255) / 256, 256, 0, stream>>>(dst1, deg1, E1, dst0, deg0,
                                                   E0);

  const int n1s = N1 + 1, B1 = (n1s + 1023) / 1024;
  const int n0s = N0 + 1, B0 = (n0s + 1023) / 1024;
  k_scanlb<<<B1 + B0, 256, 0, stream>>>(deg1, off1, woff1, fl1, n1s, B1,
                                        deg0, off0, woff0, fl0, n0s);

  k_fillm<<<(Etot + 255) / 256, 256, 0, stream>>>(
      src1, dst1, s2, woff1, csr1, E1,
      src0, dst0, s1, woff0, csr0, E0);

  // layer 0, both hops in one launch: rows [0,N1) hop1, [N1,Ntot) hop0
  k_agg128m<<<(Ntot + 3) / 4, 256, 0, stream>>>(
      features, off1, csr1, s1, off0, csr0, s0, a_all, N1, Ntot,
      kfs[1][0], kfs[1][1], khs[1][0], khs[1][1],
      kfs[0][0], kfs[0][1], khs[0][0], khs[0][1]);
  {
    dim3 g((Ntot + 127) / 128, 2);
    k_gemm1<<<g, 256, 0, stream>>>(a_all, w1t, b1, n_all, Ntot);
  }

  // layer 1: a = agg(graph0, n1, n0) ; out = a@W2+b2
  k_agg256<<<(4 * N0 + 3) / 4, 256, 0, stream>>>(
      n_all, off0, csr0, n_all + (size_t)N1 * 256, a2bf, N0,
      kfs[2][0], kfs[2][1], khs[2][0], khs[2][1]);
  k_gemm2<<<(N0 + 63) / 64, 256, 0, stream>>>(a2bf, w2th, w2tl, b2, out, N0);
}